// Round 1
// baseline (352.685 us; speedup 1.0000x reference)
//
#include <hip/hip_runtime.h>

#define NH 6      // hidden units per fcn
#define NS 16     // shear pairs in core
#define EPT 4     // elements per thread

// tanh(x) = (e^{2x} - 1) / (e^{2x} + 1); e computed via v_exp_f32.
// |2x*log2e| stays << 127 for this problem (pre-acts bounded ~9), so no
// overflow/NaN guard needed. Error ~1e-6 abs, threshold is 0.109.
__device__ __forceinline__ float fast_tanh(float x) {
    float e = __expf(2.0f * x);                       // v_mul + v_exp_f32
    return (e - 1.0f) * __builtin_amdgcn_rcpf(e + 1.0f);  // add, add, rcp, mul
}

struct W6 { float w1[NH], b1[NH], w2[NH], b2; };

__device__ __forceinline__ void load_w(W6& w,
        const float* __restrict__ W1, const float* __restrict__ b1,
        const float* __restrict__ W2, const float* __restrict__ b2,
        int off6, int off1) {
    #pragma unroll
    for (int j = 0; j < NH; ++j) {
        w.w1[j] = W1[off6 + j];   // uniform address -> scalar loads
        w.b1[j] = b1[off6 + j];
        w.w2[j] = W2[off6 + j];
    }
    w.b2 = b2[off1];
}

// dst[k] += coef * fcn(src[k])  for all EPT elements
__device__ __forceinline__ void shear(float (&dst)[EPT], const float (&src)[EPT],
                                      float coef, const W6& w) {
    #pragma unroll
    for (int k = 0; k < EPT; ++k) {
        float acc = w.b2;
        #pragma unroll
        for (int j = 0; j < NH; ++j) {
            float t = fast_tanh(fmaf(src[k], w.w1[j], w.b1[j]));
            acc = fmaf(t, w.w2[j], acc);
        }
        dst[k] = fmaf(acc, coef, dst[k]);
    }
}

__global__ __launch_bounds__(256) void LHI_81501299409121_kernel(
    const float* __restrict__ x,
    const float* __restrict__ vW1, const float* __restrict__ vb1,
    const float* __restrict__ vW2, const float* __restrict__ vb2,
    const float* __restrict__ hW1, const float* __restrict__ hb1,
    const float* __restrict__ hW2, const float* __restrict__ hb2,
    const float* __restrict__ pvW1, const float* __restrict__ pvb1,
    const float* __restrict__ pvW2, const float* __restrict__ pvb2,
    const float* __restrict__ phW1, const float* __restrict__ phb1,
    const float* __restrict__ phW2, const float* __restrict__ phb2,
    float* __restrict__ out, int B)
{
    const int tid    = blockIdx.x * blockDim.x + threadIdx.x;
    const int stride = gridDim.x * blockDim.x;

    float p[EPT], q[EPT];
    const float2* __restrict__ x2 = (const float2*)x;
    #pragma unroll
    for (int k = 0; k < EPT; ++k) {
        const int idx = tid + k * stride;
        float2 v = (idx < B) ? x2[idx] : make_float2(0.f, 0.f);
        p[k] = v.x; q[k] = v.y;
    }

    W6 pv, ph;
    load_w(pv, pvW1, pvb1, pvW2, pvb2, 0, 0);
    load_w(ph, phW1, phb1, phW2, phb2, 0, 0);

    const float Hs = 0.1f;
    const float hi = Hs / NS;

    // forward processor (sign = +1): p -= f(q)*H/2; q += f(p)*H; p -= f(q)*H/2
    shear(p, q, -0.5f * Hs, pv);
    shear(q, p,  Hs,        ph);
    shear(p, q, -0.5f * Hs, pv);

    // core: 16 leapfrog shear steps with per-step weights
    #pragma unroll 1
    for (int s = 0; s < NS; ++s) {
        W6 wv, wh;
        load_w(wv, vW1, vb1, vW2, vb2, s * NH, s);
        load_w(wh, hW1, hb1, hW2, hb2, s * NH, s);
        shear(p, q, -0.5f * hi, wv);
        shear(q, p,  hi,        wh);
        shear(p, q, -0.5f * hi, wv);
    }

    // backward processor (sign = -1)
    shear(p, q,  0.5f * Hs, pv);
    shear(q, p, -Hs,        ph);
    shear(p, q,  0.5f * Hs, pv);

    float2* __restrict__ o2 = (float2*)out;
    #pragma unroll
    for (int k = 0; k < EPT; ++k) {
        const int idx = tid + k * stride;
        if (idx < B) o2[idx] = make_float2(p[k], q[k]);
    }
}

extern "C" void kernel_launch(void* const* d_in, const int* in_sizes, int n_in,
                              void* d_out, int out_size, void* d_ws, size_t ws_size,
                              hipStream_t stream) {
    const int B = in_sizes[0] / 2;           // x is [B,2]
    const int block = 256;
    const int grid = (B + block * EPT - 1) / (block * EPT);
    LHI_81501299409121_kernel<<<grid, block, 0, stream>>>(
        (const float*)d_in[0],
        (const float*)d_in[1],  (const float*)d_in[2],
        (const float*)d_in[3],  (const float*)d_in[4],
        (const float*)d_in[5],  (const float*)d_in[6],
        (const float*)d_in[7],  (const float*)d_in[8],
        (const float*)d_in[9],  (const float*)d_in[10],
        (const float*)d_in[11], (const float*)d_in[12],
        (const float*)d_in[13], (const float*)d_in[14],
        (const float*)d_in[15], (const float*)d_in[16],
        (float*)d_out, B);
}

// Round 2
// 57.287 us; speedup vs baseline: 6.1564x; 6.1564x over previous
//
#include <hip/hip_runtime.h>

#define NH 6
#define NS 16
#define GN 97              // table nodes per axis
#define GC 96              // cells per axis
#define LIM 6.0f           // fast-path input bound
#define ORIG -6.08f        // grid origin
#define DLT 0.12666667f    // (2*6.08)/GC
#define INV_D 7.8947368f   // GC/(2*6.08)
#define TAB_OFF 48.0f      // -ORIG*INV_D (u = p*INV_D + TAB_OFF)
#define EPT 4
#define BLK 1024

struct P16 {
    const float *vW1,*vb1,*vW2,*vb2, *hW1,*hb1,*hW2,*hb2;
    const float *pvW1,*pvb1,*pvW2,*pvb2, *phW1,*phb1,*phW2,*phb2;
};

__device__ __forceinline__ float fcn6(float x,
        const float* __restrict__ W1, const float* __restrict__ b1,
        const float* __restrict__ W2, float b2v) {
    float acc = b2v;
    #pragma unroll
    for (int j = 0; j < NH; ++j)
        acc = fmaf(tanhf(fmaf(x, W1[j], b1[j])), W2[j], acc);
    return acc;
}

// Exact 54-shear map (used by table precompute and rare out-of-range path).
__device__ void full_map(float& p, float& q, const P16& w) {
    const float Hs = 0.1f;
    const float hi = Hs / NS;
    // forward processor (sign = +1)
    p = fmaf(fcn6(q, w.pvW1, w.pvb1, w.pvW2, w.pvb2[0]), -0.5f * Hs, p);
    q = fmaf(fcn6(p, w.phW1, w.phb1, w.phW2, w.phb2[0]),         Hs, q);
    p = fmaf(fcn6(q, w.pvW1, w.pvb1, w.pvW2, w.pvb2[0]), -0.5f * Hs, p);
    // core
    for (int s = 0; s < NS; ++s) {
        const float* a1 = w.vW1 + s * NH;
        const float* c1 = w.vb1 + s * NH;
        const float* a2 = w.vW2 + s * NH;
        const float* d1 = w.hW1 + s * NH;
        const float* e1 = w.hb1 + s * NH;
        const float* d2 = w.hW2 + s * NH;
        p = fmaf(fcn6(q, a1, c1, a2, w.vb2[s]), -0.5f * hi, p);
        q = fmaf(fcn6(p, d1, e1, d2, w.hb2[s]),         hi, q);
        p = fmaf(fcn6(q, a1, c1, a2, w.vb2[s]), -0.5f * hi, p);
    }
    // backward processor (sign = -1)
    p = fmaf(fcn6(q, w.pvW1, w.pvb1, w.pvW2, w.pvb2[0]),  0.5f * Hs, p);
    q = fmaf(fcn6(p, w.phW1, w.phb1, w.phW2, w.phb2[0]),        -Hs, q);
    p = fmaf(fcn6(q, w.pvW1, w.pvb1, w.pvW2, w.pvb2[0]),  0.5f * Hs, p);
}

// --- precompute: exact map at 97x97 grid nodes -> d_ws ---
__global__ void LHI_build_table(float2* __restrict__ tg, P16 w) {
    const int n = blockIdx.x * blockDim.x + threadIdx.x;
    if (n >= GN * GN) return;
    const int i = n % GN, j = n / GN;
    float p = fmaf((float)i, DLT, ORIG);
    float q = fmaf((float)j, DLT, ORIG);
    full_map(p, q, w);
    tg[n] = make_float2(p, q);
}

// --- main: bilinear lookup from LDS-staged table ---
__global__ __launch_bounds__(BLK) void LHI_81501299409121_kernel(
        const float* __restrict__ x, const float2* __restrict__ tg,
        P16 w, float* __restrict__ out, int B) {
    __shared__ float2 tab[GN * GN];
    for (int n = threadIdx.x; n < GN * GN; n += BLK) tab[n] = tg[n];
    __syncthreads();

    const int tid    = blockIdx.x * BLK + threadIdx.x;
    const int stride = gridDim.x * BLK;
    const float2* __restrict__ x2 = (const float2*)x;
    float2* __restrict__ o2 = (float2*)out;

    #pragma unroll
    for (int k = 0; k < EPT; ++k) {
        const int idx = tid + k * stride;
        if (idx < B) {
            float2 v = x2[idx];
            float p = v.x, q = v.y;
            if (fabsf(p) <= LIM && fabsf(q) <= LIM) {
                const float u  = fmaf(p, INV_D, TAB_OFF);  // in [0.63, 95.37]
                const float vv = fmaf(q, INV_D, TAB_OFF);
                const float fu = floorf(u), fv = floorf(vv);
                const int i0 = (int)fu, j0 = (int)fv;
                const float du = u - fu, dv = vv - fv;
                const int n00 = j0 * GN + i0;
                const float2 c00 = tab[n00],      c10 = tab[n00 + 1];
                const float2 c01 = tab[n00 + GN], c11 = tab[n00 + GN + 1];
                const float px0 = fmaf(du, c10.x - c00.x, c00.x);
                const float px1 = fmaf(du, c11.x - c01.x, c01.x);
                p = fmaf(dv, px1 - px0, px0);
                const float qx0 = fmaf(du, c10.y - c00.y, c00.y);
                const float qx1 = fmaf(du, c11.y - c01.y, c01.y);
                q = fmaf(dv, qx1 - qx0, qx0);
            } else {
                full_map(p, q, w);   // rare: execz-skipped when no lane triggers
            }
            o2[idx] = make_float2(p, q);
        }
    }
}

// --- fallback if workspace can't hold the table ---
__global__ __launch_bounds__(256) void LHI_direct_kernel(
        const float* __restrict__ x, P16 w, float* __restrict__ out, int B) {
    const int idx = blockIdx.x * 256 + threadIdx.x;
    if (idx >= B) return;
    float2 v = ((const float2*)x)[idx];
    float p = v.x, q = v.y;
    full_map(p, q, w);
    ((float2*)out)[idx] = make_float2(p, q);
}

extern "C" void kernel_launch(void* const* d_in, const int* in_sizes, int n_in,
                              void* d_out, int out_size, void* d_ws, size_t ws_size,
                              hipStream_t stream) {
    const int B = in_sizes[0] / 2;   // x is [B,2]
    P16 w;
    w.vW1  = (const float*)d_in[1];  w.vb1  = (const float*)d_in[2];
    w.vW2  = (const float*)d_in[3];  w.vb2  = (const float*)d_in[4];
    w.hW1  = (const float*)d_in[5];  w.hb1  = (const float*)d_in[6];
    w.hW2  = (const float*)d_in[7];  w.hb2  = (const float*)d_in[8];
    w.pvW1 = (const float*)d_in[9];  w.pvb1 = (const float*)d_in[10];
    w.pvW2 = (const float*)d_in[11]; w.pvb2 = (const float*)d_in[12];
    w.phW1 = (const float*)d_in[13]; w.phb1 = (const float*)d_in[14];
    w.phW2 = (const float*)d_in[15]; w.phb2 = (const float*)d_in[16];
    const float* x = (const float*)d_in[0];
    float* out = (float*)d_out;

    const size_t tab_bytes = (size_t)GN * GN * sizeof(float2);
    if (ws_size >= tab_bytes) {
        float2* tg = (float2*)d_ws;
        LHI_build_table<<<(GN * GN + 255) / 256, 256, 0, stream>>>(tg, w);
        const int grid = (B + BLK * EPT - 1) / (BLK * EPT);
        LHI_81501299409121_kernel<<<grid, BLK, 0, stream>>>(x, tg, w, out, B);
    } else {
        LHI_direct_kernel<<<(B + 255) / 256, 256, 0, stream>>>(x, w, out, B);
    }
}

// Round 3
// 38.561 us; speedup vs baseline: 9.1461x; 1.4856x over previous
//
#include <hip/hip_runtime.h>

#define NH 6
#define NS 16
#define GN 97              // table nodes per axis
#define GC 96              // cells per axis
#define LIM 6.0f           // fast-path input bound
#define ORIG -6.08f        // grid origin
#define DLT 0.12666667f    // (2*6.08)/GC
#define INV_D 7.8947368f   // GC/(2*6.08)
#define TAB_OFF 48.0f      // -ORIG*INV_D (u = p*INV_D + TAB_OFF)
#define EPT 4
#define BLK 1024

struct P16 {
    const float *vW1,*vb1,*vW2,*vb2, *hW1,*hb1,*hW2,*hb2;
    const float *pvW1,*pvb1,*pvW2,*pvb2, *phW1,*phb1,*phW2,*phb2;
};

// tanh(x) = (e^{2x} - 1) / (e^{2x} + 1). Pre-activations here are bounded
// (|arg| < ~10) so no overflow guard needed; abs error ~1e-6, table needs 1e-3.
__device__ __forceinline__ float fast_tanh(float x) {
    float e = __expf(2.0f * x);
    return (e - 1.0f) * __builtin_amdgcn_rcpf(e + 1.0f);
}

__device__ __forceinline__ float fcn6(float x,
        const float* __restrict__ W1, const float* __restrict__ b1,
        const float* __restrict__ W2, float b2v) {
    float acc = b2v;
    #pragma unroll
    for (int j = 0; j < NH; ++j)
        acc = fmaf(fast_tanh(fmaf(x, W1[j], b1[j])), W2[j], acc);
    return acc;
}

// Exact 54-shear map (table precompute and rare out-of-range path).
__device__ void full_map(float& p, float& q, const P16& w) {
    const float Hs = 0.1f;
    const float hi = Hs / NS;
    // forward processor (sign = +1)
    p = fmaf(fcn6(q, w.pvW1, w.pvb1, w.pvW2, w.pvb2[0]), -0.5f * Hs, p);
    q = fmaf(fcn6(p, w.phW1, w.phb1, w.phW2, w.phb2[0]),         Hs, q);
    p = fmaf(fcn6(q, w.pvW1, w.pvb1, w.pvW2, w.pvb2[0]), -0.5f * Hs, p);
    // core
    for (int s = 0; s < NS; ++s) {
        const float* a1 = w.vW1 + s * NH;
        const float* c1 = w.vb1 + s * NH;
        const float* a2 = w.vW2 + s * NH;
        const float* d1 = w.hW1 + s * NH;
        const float* e1 = w.hb1 + s * NH;
        const float* d2 = w.hW2 + s * NH;
        p = fmaf(fcn6(q, a1, c1, a2, w.vb2[s]), -0.5f * hi, p);
        q = fmaf(fcn6(p, d1, e1, d2, w.hb2[s]),         hi, q);
        p = fmaf(fcn6(q, a1, c1, a2, w.vb2[s]), -0.5f * hi, p);
    }
    // backward processor (sign = -1)
    p = fmaf(fcn6(q, w.pvW1, w.pvb1, w.pvW2, w.pvb2[0]),  0.5f * Hs, p);
    q = fmaf(fcn6(p, w.phW1, w.phb1, w.phW2, w.phb2[0]),        -Hs, q);
    p = fmaf(fcn6(q, w.pvW1, w.pvb1, w.pvW2, w.pvb2[0]),  0.5f * Hs, p);
}

// --- precompute: exact map at 97x97 grid nodes -> d_ws ---
__global__ __launch_bounds__(256) void LHI_build_table(float2* __restrict__ tg, P16 w) {
    const int n = blockIdx.x * blockDim.x + threadIdx.x;
    if (n >= GN * GN) return;
    const int i = n % GN, j = n / GN;
    float p = fmaf((float)i, DLT, ORIG);
    float q = fmaf((float)j, DLT, ORIG);
    full_map(p, q, w);
    tg[n] = make_float2(p, q);
}

// --- main: bilinear lookup from LDS-staged table ---
__global__ __launch_bounds__(BLK) void LHI_81501299409121_kernel(
        const float* __restrict__ x, const float2* __restrict__ tg,
        P16 w, float* __restrict__ out, int B) {
    __shared__ float2 tab[GN * GN];
    for (int n = threadIdx.x; n < GN * GN; n += BLK) tab[n] = tg[n];
    __syncthreads();

    const int tid    = blockIdx.x * BLK + threadIdx.x;
    const int stride = gridDim.x * BLK;
    const float2* __restrict__ x2 = (const float2*)x;
    float2* __restrict__ o2 = (float2*)out;

    #pragma unroll
    for (int k = 0; k < EPT; ++k) {
        const int idx = tid + k * stride;
        if (idx < B) {
            float2 v = x2[idx];
            float p = v.x, q = v.y;
            if (fabsf(p) <= LIM && fabsf(q) <= LIM) {
                const float u  = fmaf(p, INV_D, TAB_OFF);  // in [0.63, 95.37]
                const float vv = fmaf(q, INV_D, TAB_OFF);
                const float fu = floorf(u), fv = floorf(vv);
                const int i0 = (int)fu, j0 = (int)fv;
                const float du = u - fu, dv = vv - fv;
                const int n00 = j0 * GN + i0;
                const float2 c00 = tab[n00],      c10 = tab[n00 + 1];
                const float2 c01 = tab[n00 + GN], c11 = tab[n00 + GN + 1];
                const float px0 = fmaf(du, c10.x - c00.x, c00.x);
                const float px1 = fmaf(du, c11.x - c01.x, c01.x);
                p = fmaf(dv, px1 - px0, px0);
                const float qx0 = fmaf(du, c10.y - c00.y, c00.y);
                const float qx1 = fmaf(du, c11.y - c01.y, c01.y);
                q = fmaf(dv, qx1 - qx0, qx0);
            } else {
                full_map(p, q, w);   // rare: execz-skipped when no lane triggers
            }
            o2[idx] = make_float2(p, q);
        }
    }
}

// --- fallback if workspace can't hold the table ---
__global__ __launch_bounds__(256) void LHI_direct_kernel(
        const float* __restrict__ x, P16 w, float* __restrict__ out, int B) {
    const int idx = blockIdx.x * 256 + threadIdx.x;
    if (idx >= B) return;
    float2 v = ((const float2*)x)[idx];
    float p = v.x, q = v.y;
    full_map(p, q, w);
    ((float2*)out)[idx] = make_float2(p, q);
}

extern "C" void kernel_launch(void* const* d_in, const int* in_sizes, int n_in,
                              void* d_out, int out_size, void* d_ws, size_t ws_size,
                              hipStream_t stream) {
    const int B = in_sizes[0] / 2;   // x is [B,2]
    P16 w;
    w.vW1  = (const float*)d_in[1];  w.vb1  = (const float*)d_in[2];
    w.vW2  = (const float*)d_in[3];  w.vb2  = (const float*)d_in[4];
    w.hW1  = (const float*)d_in[5];  w.hb1  = (const float*)d_in[6];
    w.hW2  = (const float*)d_in[7];  w.hb2  = (const float*)d_in[8];
    w.pvW1 = (const float*)d_in[9];  w.pvb1 = (const float*)d_in[10];
    w.pvW2 = (const float*)d_in[11]; w.pvb2 = (const float*)d_in[12];
    w.phW1 = (const float*)d_in[13]; w.phb1 = (const float*)d_in[14];
    w.phW2 = (const float*)d_in[15]; w.phb2 = (const float*)d_in[16];
    const float* x = (const float*)d_in[0];
    float* out = (float*)d_out;

    const size_t tab_bytes = (size_t)GN * GN * sizeof(float2);
    if (ws_size >= tab_bytes) {
        float2* tg = (float2*)d_ws;
        LHI_build_table<<<(GN * GN + 255) / 256, 256, 0, stream>>>(tg, w);
        const int grid = (B + BLK * EPT - 1) / (BLK * EPT);
        LHI_81501299409121_kernel<<<grid, BLK, 0, stream>>>(x, tg, w, out, B);
    } else {
        LHI_direct_kernel<<<(B + 255) / 256, 256, 0, stream>>>(x, w, out, B);
    }
}

// Round 4
// 35.831 us; speedup vs baseline: 9.8429x; 1.0762x over previous
//
#include <hip/hip_runtime.h>
#include <hip/hip_fp16.h>

#define NH 6
#define NS 16
#define GN 97              // table nodes per axis
#define GC 96              // cells per axis
#define LIM 6.0f           // fast-path input bound
#define ORIG -6.08f        // grid origin
#define DLT 0.12666667f    // (2*6.08)/GC
#define INV_D 7.8947368f   // GC/(2*6.08)
#define TAB_OFF 48.0f      // -ORIG*INV_D (u = p*INV_D + TAB_OFF)
#define BLK 1024
#define NBLK 512           // persistent: 2 blocks/CU on 256 CUs

struct P16 {
    const float *vW1,*vb1,*vW2,*vb2, *hW1,*hb1,*hW2,*hb2;
    const float *pvW1,*pvb1,*pvW2,*pvb2, *phW1,*phb1,*phW2,*phb2;
};

// tanh(x) = (e^{2x} - 1) / (e^{2x} + 1). Pre-activations bounded (|arg|<~10),
// no overflow guard needed; abs err ~1e-6 (table only needs ~1e-3).
__device__ __forceinline__ float fast_tanh(float x) {
    float e = __expf(2.0f * x);
    return (e - 1.0f) * __builtin_amdgcn_rcpf(e + 1.0f);
}

__device__ __forceinline__ float fcn6(float x,
        const float* __restrict__ W1, const float* __restrict__ b1,
        const float* __restrict__ W2, float b2v) {
    float acc = b2v;
    #pragma unroll
    for (int j = 0; j < NH; ++j)
        acc = fmaf(fast_tanh(fmaf(x, W1[j], b1[j])), W2[j], acc);
    return acc;
}

// Exact 54-shear map (table precompute and rare out-of-range path).
__device__ void full_map(float& p, float& q, const P16& w) {
    const float Hs = 0.1f;
    const float hi = Hs / NS;
    p = fmaf(fcn6(q, w.pvW1, w.pvb1, w.pvW2, w.pvb2[0]), -0.5f * Hs, p);
    q = fmaf(fcn6(p, w.phW1, w.phb1, w.phW2, w.phb2[0]),         Hs, q);
    p = fmaf(fcn6(q, w.pvW1, w.pvb1, w.pvW2, w.pvb2[0]), -0.5f * Hs, p);
    for (int s = 0; s < NS; ++s) {
        const float* a1 = w.vW1 + s * NH;
        const float* c1 = w.vb1 + s * NH;
        const float* a2 = w.vW2 + s * NH;
        const float* d1 = w.hW1 + s * NH;
        const float* e1 = w.hb1 + s * NH;
        const float* d2 = w.hW2 + s * NH;
        p = fmaf(fcn6(q, a1, c1, a2, w.vb2[s]), -0.5f * hi, p);
        q = fmaf(fcn6(p, d1, e1, d2, w.hb2[s]),         hi, q);
        p = fmaf(fcn6(q, a1, c1, a2, w.vb2[s]), -0.5f * hi, p);
    }
    p = fmaf(fcn6(q, w.pvW1, w.pvb1, w.pvW2, w.pvb2[0]),  0.5f * Hs, p);
    q = fmaf(fcn6(p, w.phW1, w.phb1, w.phW2, w.phb2[0]),        -Hs, q);
    p = fmaf(fcn6(q, w.pvW1, w.pvb1, w.pvW2, w.pvb2[0]),  0.5f * Hs, p);
}

// --- precompute: delta map (p'-p, q'-q) at 97x97 grid nodes, packed f16x2 ---
__global__ __launch_bounds__(256) void LHI_build_table(__half2* __restrict__ tg, P16 w) {
    const int n = blockIdx.x * blockDim.x + threadIdx.x;
    if (n >= GN * GN) return;
    const int i = n % GN, j = n / GN;
    const float p0 = fmaf((float)i, DLT, ORIG);
    const float q0 = fmaf((float)j, DLT, ORIG);
    float p = p0, q = q0;
    full_map(p, q, w);
    tg[n] = __floats2half2_rn(p - p0, q - q0);   // |delta| <= ~1, f16 err ~5e-4
}

// --- main: persistent grid-stride, bilinear delta lookup from LDS ---
__global__ __launch_bounds__(BLK) void LHI_81501299409121_kernel(
        const float* __restrict__ x, const __half2* __restrict__ tg,
        P16 w, float* __restrict__ out, int B) {
    __shared__ __half2 tab[GN * GN];
    for (int n = threadIdx.x; n < GN * GN; n += BLK) tab[n] = tg[n];
    __syncthreads();

    const int tid0   = blockIdx.x * BLK + threadIdx.x;
    const int stride = NBLK * BLK;
    const float2* __restrict__ x2 = (const float2*)x;
    float2* __restrict__ o2 = (float2*)out;

    for (int idx = tid0; idx < B; idx += stride) {
        float2 v = x2[idx];
        float p = v.x, q = v.y;
        if (fabsf(p) <= LIM && fabsf(q) <= LIM) {
            const float u  = fmaf(p, INV_D, TAB_OFF);   // in [0.63, 95.37]
            const float vv = fmaf(q, INV_D, TAB_OFF);
            const float fu = floorf(u), fv = floorf(vv);
            const int i0 = (int)fu, j0 = (int)fv;
            const float du = u - fu, dv = vv - fv;
            const int n00 = j0 * GN + i0;
            const float2 c00 = __half22float2(tab[n00]);
            const float2 c10 = __half22float2(tab[n00 + 1]);
            const float2 c01 = __half22float2(tab[n00 + GN]);
            const float2 c11 = __half22float2(tab[n00 + GN + 1]);
            const float px0 = fmaf(du, c10.x - c00.x, c00.x);
            const float px1 = fmaf(du, c11.x - c01.x, c01.x);
            p += fmaf(dv, px1 - px0, px0);
            const float qx0 = fmaf(du, c10.y - c00.y, c00.y);
            const float qx1 = fmaf(du, c11.y - c01.y, c01.y);
            q += fmaf(dv, qx1 - qx0, qx0);
        } else {
            full_map(p, q, w);   // rare: execz-skipped when no lane triggers
        }
        o2[idx] = make_float2(p, q);
    }
}

// --- fallback if workspace can't hold the table ---
__global__ __launch_bounds__(256) void LHI_direct_kernel(
        const float* __restrict__ x, P16 w, float* __restrict__ out, int B) {
    const int idx = blockIdx.x * 256 + threadIdx.x;
    if (idx >= B) return;
    float2 v = ((const float2*)x)[idx];
    float p = v.x, q = v.y;
    full_map(p, q, w);
    ((float2*)out)[idx] = make_float2(p, q);
}

extern "C" void kernel_launch(void* const* d_in, const int* in_sizes, int n_in,
                              void* d_out, int out_size, void* d_ws, size_t ws_size,
                              hipStream_t stream) {
    const int B = in_sizes[0] / 2;   // x is [B,2]
    P16 w;
    w.vW1  = (const float*)d_in[1];  w.vb1  = (const float*)d_in[2];
    w.vW2  = (const float*)d_in[3];  w.vb2  = (const float*)d_in[4];
    w.hW1  = (const float*)d_in[5];  w.hb1  = (const float*)d_in[6];
    w.hW2  = (const float*)d_in[7];  w.hb2  = (const float*)d_in[8];
    w.pvW1 = (const float*)d_in[9];  w.pvb1 = (const float*)d_in[10];
    w.pvW2 = (const float*)d_in[11]; w.pvb2 = (const float*)d_in[12];
    w.phW1 = (const float*)d_in[13]; w.phb1 = (const float*)d_in[14];
    w.phW2 = (const float*)d_in[15]; w.phb2 = (const float*)d_in[16];
    const float* x = (const float*)d_in[0];
    float* out = (float*)d_out;

    const size_t tab_bytes = (size_t)GN * GN * sizeof(__half2);
    if (ws_size >= tab_bytes) {
        __half2* tg = (__half2*)d_ws;
        LHI_build_table<<<(GN * GN + 255) / 256, 256, 0, stream>>>(tg, w);
        LHI_81501299409121_kernel<<<NBLK, BLK, 0, stream>>>(x, tg, w, out, B);
    } else {
        LHI_direct_kernel<<<(B + 255) / 256, 256, 0, stream>>>(x, w, out, B);
    }
}